// Round 14
// baseline (184.748 us; speedup 1.0000x reference)
//
#include <hip/hip_runtime.h>
#include <hip/hip_fp16.h>

#define NN 100000
#define NB 391        // ceil(NN/256) buckets of 256 dst nodes
#define NG 512        // edge-pass blocks
#define REGION 6144   // padded per-bucket staging/csr region
#define BINCAP 16384  // padded per-degree-bin region in order[]
#define GRID_T 6314   // N/16 + 64 slack tiles

using f16x8 = __attribute__((ext_vector_type(8))) _Float16;
using f32x4 = __attribute__((ext_vector_type(4))) float;

// ---------------- pass A: per-block bucket histogram (LDS), counts[NG][NB]; init bincur ----------------
__global__ __launch_bounds__(256) void bhist_kernel(const int* __restrict__ dst,
                                                    int* __restrict__ counts,
                                                    int* __restrict__ bincur, int E) {
    if (blockIdx.x == 0 && threadIdx.x < 64) bincur[threadIdx.x] = threadIdx.x * BINCAP;
    __shared__ int h[NB];
    for (int i = threadIdx.x; i < NB; i += 256) h[i] = 0;
    __syncthreads();
    const int g = blockIdx.x;
    const int chunk = (E + NG - 1) / NG;
    const int lo = g * chunk, hi = min(E, lo + chunk);
    for (int e = lo + threadIdx.x; e < hi; e += 256) atomicAdd(&h[dst[e] >> 8], 1);
    __syncthreads();
    for (int i = threadIdx.x; i < NB; i += 256) counts[g * NB + i] = h[i];
}

// ---------------- pass B: per-bucket prefix over NG entries (padded regions) + folded cvtW ----------------
__global__ __launch_bounds__(256) void bprefix_kernel(int* __restrict__ counts,
                                                      int* __restrict__ btot,
                                                      const float* __restrict__ W1,
                                                      const float* __restrict__ W2,
                                                      __half* __restrict__ W1t,
                                                      __half* __restrict__ W2t) {
    const int b = blockIdx.x, t = threadIdx.x;
    if (b == NB) {
        for (int i = t; i < 64 * 128; i += 256) {
            int k = i / 128, c = i % 128;
            W1t[c * 64 + k] = __float2half(W1[i]);
            int k2 = i / 64, c2 = i % 64;
            W2t[c2 * 128 + k2] = __float2half(W2[i]);
        }
        return;
    }
    __shared__ int sm[256];
    int loc[NG / 256];
    int s = 0;
    #pragma unroll
    for (int p = 0; p < NG / 256; ++p) {
        loc[p] = counts[((NG / 256) * t + p) * NB + b];
        s += loc[p];
    }
    sm[t] = s; __syncthreads();
    for (int off = 1; off < 256; off <<= 1) {
        int x = (t >= off) ? sm[t - off] : 0; __syncthreads();
        sm[t] += x; __syncthreads();
    }
    int run = b * REGION + sm[t] - s;
    #pragma unroll
    for (int p = 0; p < NG / 256; ++p) {
        int c = loc[p];
        counts[((NG / 256) * t + p) * NB + b] = run;
        run += c;
    }
    if (t == 255) btot[b] = sm[255];
}

// ---------------- pass C: scatter edges into bucket-region staging ----------------
__global__ __launch_bounds__(256) void bscatter_kernel(const int* __restrict__ src,
                                                       const int* __restrict__ dst,
                                                       const int* __restrict__ cstart,
                                                       int* __restrict__ staging, int E) {
    __shared__ int cur[NB];
    const int g = blockIdx.x;
    for (int i = threadIdx.x; i < NB; i += 256) cur[i] = cstart[g * NB + i];
    __syncthreads();
    const int chunk = (E + NG - 1) / NG;
    const int lo = g * chunk, hi = min(E, lo + chunk);
    for (int e = lo + threadIdx.x; e < hi; e += 256) {
        int d = dst[e];
        int pos = atomicAdd(&cur[d >> 8], 1);
        staging[pos] = src[e] | ((d & 255) << 17);
    }
}

// ---------------- pass D: CSR finalize + row_beg/end + dis + x->fp16 + degree binning ----------------
__global__ __launch_bounds__(256) void bfinal_kernel(const int* __restrict__ btot,
                                                     const int* __restrict__ staging,
                                                     int* __restrict__ csr,
                                                     int* __restrict__ row_beg,
                                                     int* __restrict__ row_end,
                                                     float* __restrict__ dis,
                                                     const float* __restrict__ x,
                                                     __half* __restrict__ xh,
                                                     int* __restrict__ bincur,
                                                     int* __restrict__ order,
                                                     int N) {
    __shared__ int h[256];
    __shared__ int sc[256];
    __shared__ int cur[256];
    __shared__ float sdis[256];
    __shared__ int bh[64], lbase[64], lcnt[64];
    const int b = blockIdx.x, t = threadIdx.x;
    const int base = b * REGION;
    const int endb = base + btot[b];
    h[t] = 0;
    if (t < 64) { bh[t] = 0; lcnt[t] = 0; }
    __syncthreads();
    for (int i = base + t; i < endb; i += 256) atomicAdd(&h[staging[i] >> 17], 1);
    __syncthreads();
    int v = h[t];
    sc[t] = v; __syncthreads();
    for (int off = 1; off < 256; off <<= 1) {
        int xv = (t >= off) ? sc[t - off] : 0; __syncthreads();
        sc[t] += xv; __syncthreads();
    }
    int excl = sc[t] - v;
    cur[t] = base + excl;
    float dv = rsqrtf((float)v + 1.0f);
    sdis[t] = dv;
    int node = b * 256 + t;
    int bin = -1;
    if (node < N) {
        row_beg[node] = base + excl;
        row_end[node] = base + excl + v;
        dis[node] = dv;
        bin = min(v, 63);
    }
    __syncthreads();
    for (int i = base + t; i < endb; i += 256) {
        int p = staging[i];
        int pos = atomicAdd(&cur[p >> 17], 1);
        csr[pos] = p & 0x1FFFF;
    }
    // fused: xh[node] = dis[node]*x[node] (fp16, row-major)
    const int node0 = b * 256;
    const int nmax = min(256, N - node0);
    for (int i = t; i < nmax * 16; i += 256) {
        int nl = i >> 4, c4 = i & 15;
        float4 vx = ((const float4*)x)[(size_t)(node0 + nl) * 16 + c4];
        float wq = sdis[nl];
        __half2* o = (__half2*)&xh[(size_t)(node0 + nl) * 64 + c4 * 4];
        o[0] = __floats2half2_rn(vx.x * wq, vx.y * wq);
        o[1] = __floats2half2_rn(vx.z * wq, vx.w * wq);
    }
    // degree binning -> order[] (padded per-bin regions)
    if (bin >= 0) atomicAdd(&bh[bin], 1);
    __syncthreads();
    if (t < 64) {
        int c = bh[t];
        lbase[t] = (c > 0) ? atomicAdd(&bincur[t], c) : 0;
    }
    __syncthreads();
    if (bin >= 0) {
        int p = lbase[bin] + atomicAdd(&lcnt[bin], 1);
        order[p] = node;
    }
}

// ---------------- tile map: compact (bin, tile) list for gfuse ----------------
__global__ __launch_bounds__(256) void tmap_kernel(const int* __restrict__ bincur,
                                                   int* __restrict__ tmap, int grid) {
    __shared__ int nt[64], ps[65];
    const int t = threadIdx.x;
    if (t < 64) nt[t] = (bincur[t] - t * BINCAP + 15) >> 4;
    __syncthreads();
    if (t == 0) {
        int s = 0;
        for (int b2 = 0; b2 < 64; ++b2) { ps[b2] = s; s += nt[b2]; }
        ps[64] = s;
    }
    __syncthreads();
    const int T = ps[64];
    for (int i = t; i < grid; i += 256) {
        int val = -1;
        if (i < T) {
            int bin = 0;
            for (int b2 = 1; b2 < 64; ++b2) if (i >= ps[b2]) bin = b2;
            val = (bin << 16) | (i - ps[bin]);
        }
        tmap[i] = val;
    }
}

// ---------------- fused layer1+layer2-GEMM over degree-uniform tiles ----------------
__global__ __launch_bounds__(512) void gfuse_kernel(const __half* __restrict__ tab,
                                                    const float* __restrict__ dis,
                                                    const __half* __restrict__ W1t,
                                                    const float* __restrict__ b1,
                                                    const __half* __restrict__ W2t,
                                                    const int* __restrict__ row_beg,
                                                    const int* __restrict__ row_end,
                                                    const int* __restrict__ csr,
                                                    const int* __restrict__ bincur,
                                                    const int* __restrict__ order,
                                                    const int* __restrict__ tmap,
                                                    __half* __restrict__ zh, int N,
                                                    float one) {
    const int tm = tmap[blockIdx.x];
    if (tm < 0) return;
    const int bin = tm >> 16, ti = tm & 0xFFFF;
    const int fill = bincur[bin] - bin * BINCAP;
    const int tbase = ti * 16;

    __shared__ _Float16 sA[16][72];
    __shared__ _Float16 sH[16][132];
    __shared__ float sP[4][16][16];
    __shared__ int snode[16];
    __shared__ float sdis16[16];
    const int tid = threadIdx.x;
    const int nodeL = tid >> 5;
    const int l32 = tid & 31;
    const int e = l32 >> 3;           // edge slot 0..3
    const int sub = l32 & 7;          // col octet
    const int nl_ok = (tbase + nodeL) < fill;
    const int node = order[bin * BINCAP + tbase + (nl_ok ? nodeL : 0)];
    if (l32 == 0) { snode[nodeL] = node; sdis16[nodeL] = dis[node]; }
    const int beg = row_beg[node], end = row_end[node];

    float acc[8];
    {   // self loop counted once via slot 0 (dis[s] folded in tab)
        f16x8 sv = *reinterpret_cast<const f16x8*>(&tab[(size_t)node * 64 + sub * 8]);
        #pragma unroll
        for (int q = 0; q < 8; ++q) acc[q] = (e == 0) ? (float)sv[q] : 0.0f;
    }
    for (int j = beg + e; j < end; j += 4) {
        int s = csr[j];
        f16x8 v = *reinterpret_cast<const f16x8*>(&tab[(size_t)s * 64 + sub * 8]);
        #pragma unroll
        for (int q = 0; q < 8; ++q) acc[q] = fmaf((float)v[q], one, acc[q]);
    }
    #pragma unroll
    for (int q = 0; q < 8; ++q) {
        acc[q] += __shfl_xor(acc[q], 8);
        acc[q] += __shfl_xor(acc[q], 16);
    }
    if (e == 0) {
        const float dd = dis[node];
        f16x8 o;
        #pragma unroll
        for (int q = 0; q < 8; ++q) o[q] = (_Float16)(acc[q] * dd);
        *reinterpret_cast<f16x8*>(&sA[nodeL][sub * 8]) = o;
    }
    __syncthreads();

    const int w = tid >> 6, lane = tid & 63;
    const int lrow = lane & 15, kgrp = lane >> 4;
    // ---- gemm1: h1 = relu(sA @ W1 + b1), 8 waves x 16 cols, K=64 ----
    {
        const int col = w * 16 + lrow;
        f32x4 a1 = (f32x4){0.f, 0.f, 0.f, 0.f};
        #pragma unroll
        for (int ks = 0; ks < 2; ++ks) {
            const int kbase = ks * 32 + kgrp * 8;
            f16x8 a  = *reinterpret_cast<const f16x8*>(&sA[lrow][kbase]);
            f16x8 bf = *reinterpret_cast<const f16x8*>(&W1t[(size_t)col * 64 + kbase]);
            a1 = __builtin_amdgcn_mfma_f32_16x16x32_f16(a, bf, a1, 0, 0, 0);
        }
        const float bb = b1[col];
        #pragma unroll
        for (int r = 0; r < 4; ++r) {
            const int row = kgrp * 4 + r;
            sH[row][col] = (_Float16)fmaxf(a1[r] + bb, 0.0f);
        }
    }
    __syncthreads();
    // ---- gemm2 split-K: zh = (sH @ W2) * dis, 4 col tiles x 2 K-halves ----
    {
        const int t2 = w & 3, kh = w >> 2;
        const int col = t2 * 16 + lrow;
        f32x4 a2 = (f32x4){0.f, 0.f, 0.f, 0.f};
        #pragma unroll
        for (int ks = 0; ks < 2; ++ks) {
            const int kbase = kh * 64 + ks * 32 + kgrp * 8;
            f16x8 a  = *reinterpret_cast<const f16x8*>(&sH[lrow][kbase]);
            f16x8 bf = *reinterpret_cast<const f16x8*>(&W2t[(size_t)col * 128 + kbase]);
            a2 = __builtin_amdgcn_mfma_f32_16x16x32_f16(a, bf, a2, 0, 0, 0);
        }
        if (kh == 1) {
            #pragma unroll
            for (int r = 0; r < 4; ++r) sP[t2][kgrp * 4 + r][lrow] = a2[r];
        }
        __syncthreads();
        if (kh == 0) {
            #pragma unroll
            for (int r = 0; r < 4; ++r) {
                const int row = kgrp * 4 + r;
                if (tbase + row < fill) {
                    int nd = snode[row];
                    float vv = (a2[r] + sP[t2][row][lrow]) * sdis16[row];
                    zh[(size_t)nd * 64 + col] = __float2half(vv);
                }
            }
        }
    }
}

// ---------------- gather2: 1 wave/node, 16 edges/iter, out fp32 + bias ----------------
__global__ __launch_bounds__(256) void gather2_kernel(const __half* __restrict__ tab,
                                                      const float* __restrict__ dis,
                                                      const float* __restrict__ b,
                                                      const int* __restrict__ row_beg,
                                                      const int* __restrict__ row_end,
                                                      const int* __restrict__ csr,
                                                      float* __restrict__ out, int N,
                                                      float one) {
    const int node = blockIdx.x * 4 + (threadIdx.x >> 6);
    const int lane = threadIdx.x & 63;
    const int g   = lane >> 3;
    const int sub = lane & 7;
    if (node >= N) return;
    const int beg = row_beg[node], end = row_end[node];

    float acc[8];
    {
        f16x8 sv = *reinterpret_cast<const f16x8*>(&tab[(size_t)node * 64 + sub * 8]);
        #pragma unroll
        for (int q = 0; q < 8; ++q) acc[q] = (g == 0) ? (float)sv[q] : 0.0f;
    }
    int j = beg;
    for (; j + 16 <= end; j += 16) {
        int sA = csr[j + g];
        int sB = csr[j + 8 + g];
        f16x8 vA = *reinterpret_cast<const f16x8*>(&tab[(size_t)sA * 64 + sub * 8]);
        f16x8 vB = *reinterpret_cast<const f16x8*>(&tab[(size_t)sB * 64 + sub * 8]);
        #pragma unroll
        for (int q = 0; q < 8; ++q) acc[q] = fmaf((float)vA[q], one, acc[q]);
        #pragma unroll
        for (int q = 0; q < 8; ++q) acc[q] = fmaf((float)vB[q], one, acc[q]);
    }
    if (j + 8 <= end) {
        int s = csr[j + g];
        f16x8 v = *reinterpret_cast<const f16x8*>(&tab[(size_t)s * 64 + sub * 8]);
        #pragma unroll
        for (int q = 0; q < 8; ++q) acc[q] = fmaf((float)v[q], one, acc[q]);
        j += 8;
    }
    if (j + g < end) {
        int s = csr[j + g];
        f16x8 v = *reinterpret_cast<const f16x8*>(&tab[(size_t)s * 64 + sub * 8]);
        #pragma unroll
        for (int q = 0; q < 8; ++q) acc[q] = fmaf((float)v[q], one, acc[q]);
    }
    #pragma unroll
    for (int q = 0; q < 8; ++q) {
        acc[q] += __shfl_xor(acc[q], 8);
        acc[q] += __shfl_xor(acc[q], 16);
        acc[q] += __shfl_xor(acc[q], 32);
    }
    if (g == 0) {
        const float dd = dis[node];
        float vv[8];
        #pragma unroll
        for (int q = 0; q < 8; ++q) vv[q] = acc[q] * dd + b[sub * 8 + q];
        float* op = &out[(size_t)node * 64 + sub * 8];
        *reinterpret_cast<float4*>(op)     = make_float4(vv[0], vv[1], vv[2], vv[3]);
        *reinterpret_cast<float4*>(op + 4) = make_float4(vv[4], vv[5], vv[6], vv[7]);
    }
}

extern "C" void kernel_launch(void* const* d_in, const int* in_sizes, int n_in,
                              void* d_out, int out_size, void* d_ws, size_t ws_size,
                              hipStream_t stream) {
    const float* x  = (const float*)d_in[0];
    const int*   ei = (const int*)d_in[1];
    const float* W1 = (const float*)d_in[2];
    const float* b1 = (const float*)d_in[3];
    const float* W2 = (const float*)d_in[4];
    const float* b2 = (const float*)d_in[5];
    float* out = (float*)d_out;

    const int N = NN;
    const int E = in_sizes[1] / 2;
    const int* src = ei;
    const int* dst = ei + E;

    // workspace layout (4-byte words)
    int* counts   = (int*)d_ws;                       // NG*NB
    int* btot     = counts + NG * NB;                 // NB (+pad)
    int* bincur   = btot + 512;                       // 64 (+pad)
    int* tmap     = bincur + 256;                     // GRID_T (+pad)
    int* row_beg  = tmap + 8192;                      // N
    int* row_end  = row_beg + N;                      // N
    float* dis    = (float*)(row_end + N);            // N
    int* order    = (int*)(dis + N);                  // 64*BINCAP
    int* staging  = order + 64 * BINCAP;              // NB*REGION
    int* csr      = staging + (size_t)NB * REGION;    // NB*REGION
    float* base   = (float*)(csr + (size_t)NB * REGION);
    __half* xh    = (__half*)base;                        // N*64 halves
    __half* zh    = (__half*)(base + (size_t)N * 32);     // N*64 halves
    __half* W1t   = (__half*)(base + (size_t)N * 64);     // 8192 halves
    __half* W2t   = W1t + 128 * 64;                       // 8192 halves

    // ---- CSR build (R12 structure) + degree binning ----
    bhist_kernel<<<NG, 256, 0, stream>>>(dst, counts, bincur, E);
    bprefix_kernel<<<NB + 1, 256, 0, stream>>>(counts, btot, W1, W2, W1t, W2t);
    bscatter_kernel<<<NG, 256, 0, stream>>>(src, dst, counts, staging, E);
    bfinal_kernel<<<NB, 256, 0, stream>>>(btot, staging, csr, row_beg, row_end, dis, x, xh, bincur, order, N);
    tmap_kernel<<<1, 256, 0, stream>>>(bincur, tmap, GRID_T);

    // ---- fused layer1 + layer2-GEMM over degree-uniform tiles ----
    gfuse_kernel<<<GRID_T, 512, 0, stream>>>(xh, dis, W1t, b1, W2t, row_beg, row_end, csr,
                                             bincur, order, tmap, zh, N, 1.0f);

    // ---- final gather: out = gather(zh) + b2 ----
    gather2_kernel<<<N / 4, 256, 0, stream>>>(zh, dis, b2, row_beg, row_end, csr, out, N, 1.0f);
}

// Round 15
// 179.592 us; speedup vs baseline: 1.0287x; 1.0287x over previous
//
#include <hip/hip_runtime.h>
#include <hip/hip_fp16.h>

#define NN 100000
#define NB 391        // ceil(NN/256) buckets of 256 dst nodes
#define NG 512        // edge-pass blocks
#define REGION 6144   // padded per-bucket staging/csr region

using f16x8 = __attribute__((ext_vector_type(8))) _Float16;
using f32x4 = __attribute__((ext_vector_type(4))) float;

// ---------------- pass A: per-block bucket histogram (LDS), counts[NG][NB] ----------------
__global__ __launch_bounds__(256) void bhist_kernel(const int* __restrict__ dst,
                                                    int* __restrict__ counts, int E) {
    __shared__ int h[NB];
    for (int i = threadIdx.x; i < NB; i += 256) h[i] = 0;
    __syncthreads();
    const int g = blockIdx.x;
    const int chunk = (E + NG - 1) / NG;
    const int lo = g * chunk, hi = min(E, lo + chunk);
    for (int e = lo + threadIdx.x; e < hi; e += 256) atomicAdd(&h[dst[e] >> 8], 1);
    __syncthreads();
    for (int i = threadIdx.x; i < NB; i += 256) counts[g * NB + i] = h[i];
}

// ---------------- pass B: per-bucket prefix over NG entries (padded regions) + folded cvtW ----------------
__global__ __launch_bounds__(256) void bprefix_kernel(int* __restrict__ counts,
                                                      int* __restrict__ btot,
                                                      const float* __restrict__ W1,
                                                      const float* __restrict__ W2,
                                                      __half* __restrict__ W1t,
                                                      __half* __restrict__ W2t) {
    const int b = blockIdx.x, t = threadIdx.x;
    if (b == NB) {
        for (int i = t; i < 64 * 128; i += 256) {
            int k = i / 128, c = i % 128;
            W1t[c * 64 + k] = __float2half(W1[i]);
            int k2 = i / 64, c2 = i % 64;
            W2t[c2 * 128 + k2] = __float2half(W2[i]);
        }
        return;
    }
    __shared__ int sm[256];
    int loc[NG / 256];
    int s = 0;
    #pragma unroll
    for (int p = 0; p < NG / 256; ++p) {
        loc[p] = counts[((NG / 256) * t + p) * NB + b];
        s += loc[p];
    }
    sm[t] = s; __syncthreads();
    for (int off = 1; off < 256; off <<= 1) {
        int x = (t >= off) ? sm[t - off] : 0; __syncthreads();
        sm[t] += x; __syncthreads();
    }
    int run = b * REGION + sm[t] - s;
    #pragma unroll
    for (int p = 0; p < NG / 256; ++p) {
        int c = loc[p];
        counts[((NG / 256) * t + p) * NB + b] = run;
        run += c;
    }
    if (t == 255) btot[b] = sm[255];
}

// ---------------- pass C: scatter edges into bucket-region staging ----------------
__global__ __launch_bounds__(256) void bscatter_kernel(const int* __restrict__ src,
                                                       const int* __restrict__ dst,
                                                       const int* __restrict__ cstart,
                                                       int* __restrict__ staging, int E) {
    __shared__ int cur[NB];
    const int g = blockIdx.x;
    for (int i = threadIdx.x; i < NB; i += 256) cur[i] = cstart[g * NB + i];
    __syncthreads();
    const int chunk = (E + NG - 1) / NG;
    const int lo = g * chunk, hi = min(E, lo + chunk);
    for (int e = lo + threadIdx.x; e < hi; e += 256) {
        int d = dst[e];
        int pos = atomicAdd(&cur[d >> 8], 1);
        staging[pos] = src[e] | ((d & 255) << 17);
    }
}

// ---------------- pass D: per-bucket CSR finalize + row_beg/end + dis + x->fp16 ----------------
__global__ __launch_bounds__(256) void bfinal_kernel(const int* __restrict__ btot,
                                                     const int* __restrict__ staging,
                                                     int* __restrict__ csr,
                                                     int* __restrict__ row_beg,
                                                     int* __restrict__ row_end,
                                                     float* __restrict__ dis,
                                                     const float* __restrict__ x,
                                                     __half* __restrict__ xh,
                                                     int N) {
    __shared__ int h[256];
    __shared__ int sc[256];
    __shared__ int cur[256];
    __shared__ float sdis[256];
    const int b = blockIdx.x, t = threadIdx.x;
    const int base = b * REGION;
    const int endb = base + btot[b];
    h[t] = 0; __syncthreads();
    for (int i = base + t; i < endb; i += 256) atomicAdd(&h[staging[i] >> 17], 1);
    __syncthreads();
    int v = h[t];
    sc[t] = v; __syncthreads();
    for (int off = 1; off < 256; off <<= 1) {
        int xv = (t >= off) ? sc[t - off] : 0; __syncthreads();
        sc[t] += xv; __syncthreads();
    }
    int excl = sc[t] - v;
    cur[t] = base + excl;
    float dv = rsqrtf((float)v + 1.0f);
    sdis[t] = dv;
    int node = b * 256 + t;
    if (node < N) {
        row_beg[node] = base + excl;
        row_end[node] = base + excl + v;
        dis[node] = dv;
    }
    __syncthreads();
    for (int i = base + t; i < endb; i += 256) {
        int p = staging[i];
        int pos = atomicAdd(&cur[p >> 17], 1);
        csr[pos] = p & 0x1FFFF;
    }
    // fused: xh[node] = dis[node]*x[node] (fp16, row-major)
    const int node0 = b * 256;
    const int nmax = min(256, N - node0);
    for (int i = t; i < nmax * 16; i += 256) {
        int nl = i >> 4, c4 = i & 15;
        float4 vx = ((const float4*)x)[(size_t)(node0 + nl) * 16 + c4];
        float wq = sdis[nl];
        __half2* o = (__half2*)&xh[(size_t)(node0 + nl) * 64 + c4 * 4];
        o[0] = __floats2half2_rn(vx.x * wq, vx.y * wq);
        o[1] = __floats2half2_rn(vx.z * wq, vx.w * wq);
    }
}

// ---------------- fused layer1+layer2-GEMM v2: 1024 thr, 1 wave/node (gather2 layout) ----------------
// zh = (relu(gather(xh)@W1+b1) @ W2) * dis
__global__ __launch_bounds__(1024) void gfuse_kernel(const __half* __restrict__ tab,
                                                     const float* __restrict__ dis,
                                                     const __half* __restrict__ W1t,
                                                     const float* __restrict__ b1,
                                                     const __half* __restrict__ W2t,
                                                     const int* __restrict__ row_beg,
                                                     const int* __restrict__ row_end,
                                                     const int* __restrict__ csr,
                                                     __half* __restrict__ zh, int N,
                                                     float one) {
    __shared__ _Float16 sA[16][72];    // 16x64 agg tile (dis-scaled)
    __shared__ _Float16 sH[16][132];   // 16x128 h1 tile
    __shared__ float sP[12][16][16];   // split-K partials (gemm1 uses 8, gemm2 uses 12)
    __shared__ float sdis16[16];
    const int tid = threadIdx.x;
    const int wv = tid >> 6;          // 0..15 = node within tile, and MFMA wave id
    const int lane = tid & 63;
    const int g   = lane >> 3;        // edge slot 0..7
    const int sub = lane & 7;         // col octet
    const int node0 = blockIdx.x * 16;
    const int node = node0 + wv;
    const int beg = row_beg[node], end = row_end[node];

    // ---- gather phase (identical structure to gather2) ----
    float acc[8];
    {   // self loop via slot 0 (dis[s] folded in tab)
        f16x8 sv = *reinterpret_cast<const f16x8*>(&tab[(size_t)node * 64 + sub * 8]);
        #pragma unroll
        for (int q = 0; q < 8; ++q) acc[q] = (g == 0) ? (float)sv[q] : 0.0f;
    }
    int j = beg;
    for (; j + 16 <= end; j += 16) {
        int sA0 = csr[j + g];
        int sB0 = csr[j + 8 + g];
        f16x8 vA = *reinterpret_cast<const f16x8*>(&tab[(size_t)sA0 * 64 + sub * 8]);
        f16x8 vB = *reinterpret_cast<const f16x8*>(&tab[(size_t)sB0 * 64 + sub * 8]);
        #pragma unroll
        for (int q = 0; q < 8; ++q) acc[q] = fmaf((float)vA[q], one, acc[q]);
        #pragma unroll
        for (int q = 0; q < 8; ++q) acc[q] = fmaf((float)vB[q], one, acc[q]);
    }
    if (j + 8 <= end) {
        int s = csr[j + g];
        f16x8 v = *reinterpret_cast<const f16x8*>(&tab[(size_t)s * 64 + sub * 8]);
        #pragma unroll
        for (int q = 0; q < 8; ++q) acc[q] = fmaf((float)v[q], one, acc[q]);
        j += 8;
    }
    if (j + g < end) {
        int s = csr[j + g];
        f16x8 v = *reinterpret_cast<const f16x8*>(&tab[(size_t)s * 64 + sub * 8]);
        #pragma unroll
        for (int q = 0; q < 8; ++q) acc[q] = fmaf((float)v[q], one, acc[q]);
    }
    #pragma unroll
    for (int q = 0; q < 8; ++q) {
        acc[q] += __shfl_xor(acc[q], 8);
        acc[q] += __shfl_xor(acc[q], 16);
        acc[q] += __shfl_xor(acc[q], 32);
    }
    if (g == 0) {
        const float dd = dis[node];
        if (sub == 0) sdis16[wv] = dd;
        f16x8 o;
        #pragma unroll
        for (int q = 0; q < 8; ++q) o[q] = (_Float16)(acc[q] * dd);
        *reinterpret_cast<f16x8*>(&sA[wv][sub * 8]) = o;
    }
    __syncthreads();

    // ---- gemm1: h1 = relu(sA @ W1 + b1). 8 col-tiles x 2-way split-K, 1 MFMA/wave ----
    const int lrow = lane & 15, kgrp = lane >> 4;
    f32x4 a1;
    const int ct1 = wv & 7, kh1 = wv >> 3;
    {
        const int col = ct1 * 16 + lrow;
        const int kbase = kh1 * 32 + kgrp * 8;
        f16x8 a  = *reinterpret_cast<const f16x8*>(&sA[lrow][kbase]);
        f16x8 bf = *reinterpret_cast<const f16x8*>(&W1t[(size_t)col * 64 + kbase]);
        a1 = (f32x4){0.f, 0.f, 0.f, 0.f};
        a1 = __builtin_amdgcn_mfma_f32_16x16x32_f16(a, bf, a1, 0, 0, 0);
        if (kh1 == 1) {
            #pragma unroll
            for (int r = 0; r < 4; ++r) sP[ct1][kgrp * 4 + r][lrow] = a1[r];
        }
    }
    __syncthreads();
    if (kh1 == 0) {
        const int col = ct1 * 16 + lrow;
        const float bb = b1[col];
        #pragma unroll
        for (int r = 0; r < 4; ++r) {
            const int row = kgrp * 4 + r;
            sH[row][col] = (_Float16)fmaxf(a1[r] + sP[ct1][row][lrow] + bb, 0.0f);
        }
    }
    __syncthreads();

    // ---- gemm2: zh = (sH @ W2) * dis. 4 col-tiles x 4-way split-K, 1 MFMA/wave ----
    f32x4 a2;
    const int ct2 = wv & 3, kq = wv >> 2;
    {
        const int col = ct2 * 16 + lrow;
        const int kbase = kq * 32 + kgrp * 8;
        f16x8 a  = *reinterpret_cast<const f16x8*>(&sH[lrow][kbase]);
        f16x8 bf = *reinterpret_cast<const f16x8*>(&W2t[(size_t)col * 128 + kbase]);
        a2 = (f32x4){0.f, 0.f, 0.f, 0.f};
        a2 = __builtin_amdgcn_mfma_f32_16x16x32_f16(a, bf, a2, 0, 0, 0);
        if (kq > 0) {
            #pragma unroll
            for (int r = 0; r < 4; ++r) sP[(kq - 1) * 4 + ct2][kgrp * 4 + r][lrow] = a2[r];
        }
    }
    __syncthreads();
    if (kq == 0) {
        const int col = ct2 * 16 + lrow;
        #pragma unroll
        for (int r = 0; r < 4; ++r) {
            const int row = kgrp * 4 + r;
            float v = a2[r] + sP[ct2][row][lrow] + sP[4 + ct2][row][lrow] + sP[8 + ct2][row][lrow];
            zh[(size_t)(node0 + row) * 64 + col] = __float2half(v * sdis16[row]);
        }
    }
}

// ---------------- gather2: 1 wave/node, 16 edges/iter, out fp32 + bias ----------------
__global__ __launch_bounds__(256) void gather2_kernel(const __half* __restrict__ tab,
                                                      const float* __restrict__ dis,
                                                      const float* __restrict__ b,
                                                      const int* __restrict__ row_beg,
                                                      const int* __restrict__ row_end,
                                                      const int* __restrict__ csr,
                                                      float* __restrict__ out, int N,
                                                      float one) {
    const int node = blockIdx.x * 4 + (threadIdx.x >> 6);
    const int lane = threadIdx.x & 63;
    const int g   = lane >> 3;
    const int sub = lane & 7;
    if (node >= N) return;
    const int beg = row_beg[node], end = row_end[node];

    float acc[8];
    {
        f16x8 sv = *reinterpret_cast<const f16x8*>(&tab[(size_t)node * 64 + sub * 8]);
        #pragma unroll
        for (int q = 0; q < 8; ++q) acc[q] = (g == 0) ? (float)sv[q] : 0.0f;
    }
    int j = beg;
    for (; j + 16 <= end; j += 16) {
        int sA = csr[j + g];
        int sB = csr[j + 8 + g];
        f16x8 vA = *reinterpret_cast<const f16x8*>(&tab[(size_t)sA * 64 + sub * 8]);
        f16x8 vB = *reinterpret_cast<const f16x8*>(&tab[(size_t)sB * 64 + sub * 8]);
        #pragma unroll
        for (int q = 0; q < 8; ++q) acc[q] = fmaf((float)vA[q], one, acc[q]);
        #pragma unroll
        for (int q = 0; q < 8; ++q) acc[q] = fmaf((float)vB[q], one, acc[q]);
    }
    if (j + 8 <= end) {
        int s = csr[j + g];
        f16x8 v = *reinterpret_cast<const f16x8*>(&tab[(size_t)s * 64 + sub * 8]);
        #pragma unroll
        for (int q = 0; q < 8; ++q) acc[q] = fmaf((float)v[q], one, acc[q]);
        j += 8;
    }
    if (j + g < end) {
        int s = csr[j + g];
        f16x8 v = *reinterpret_cast<const f16x8*>(&tab[(size_t)s * 64 + sub * 8]);
        #pragma unroll
        for (int q = 0; q < 8; ++q) acc[q] = fmaf((float)v[q], one, acc[q]);
    }
    #pragma unroll
    for (int q = 0; q < 8; ++q) {
        acc[q] += __shfl_xor(acc[q], 8);
        acc[q] += __shfl_xor(acc[q], 16);
        acc[q] += __shfl_xor(acc[q], 32);
    }
    if (g == 0) {
        const float dd = dis[node];
        float vv[8];
        #pragma unroll
        for (int q = 0; q < 8; ++q) vv[q] = acc[q] * dd + b[sub * 8 + q];
        float* op = &out[(size_t)node * 64 + sub * 8];
        *reinterpret_cast<float4*>(op)     = make_float4(vv[0], vv[1], vv[2], vv[3]);
        *reinterpret_cast<float4*>(op + 4) = make_float4(vv[4], vv[5], vv[6], vv[7]);
    }
}

extern "C" void kernel_launch(void* const* d_in, const int* in_sizes, int n_in,
                              void* d_out, int out_size, void* d_ws, size_t ws_size,
                              hipStream_t stream) {
    const float* x  = (const float*)d_in[0];
    const int*   ei = (const int*)d_in[1];
    const float* W1 = (const float*)d_in[2];
    const float* b1 = (const float*)d_in[3];
    const float* W2 = (const float*)d_in[4];
    const float* b2 = (const float*)d_in[5];
    float* out = (float*)d_out;

    const int N = NN;
    const int E = in_sizes[1] / 2;
    const int* src = ei;
    const int* dst = ei + E;

    // workspace layout (4-byte words)
    int* counts   = (int*)d_ws;                       // NG*NB
    int* btot     = counts + NG * NB;                 // NB (+pad)
    int* row_beg  = btot + 512;                       // N
    int* row_end  = row_beg + N;                      // N
    float* dis    = (float*)(row_end + N);            // N
    int* staging  = (int*)(dis + N);                  // NB*REGION
    int* csr      = staging + (size_t)NB * REGION;    // NB*REGION
    float* base   = (float*)(csr + (size_t)NB * REGION);
    __half* xh    = (__half*)base;                        // N*64 halves
    __half* zh    = (__half*)(base + (size_t)N * 32);     // N*64 halves
    __half* W1t   = (__half*)(base + (size_t)N * 64);     // 8192 halves
    __half* W2t   = W1t + 128 * 64;                       // 8192 halves

    // ---- CSR build (R12 structure) ----
    bhist_kernel<<<NG, 256, 0, stream>>>(dst, counts, E);
    bprefix_kernel<<<NB + 1, 256, 0, stream>>>(counts, btot, W1, W2, W1t, W2t);
    bscatter_kernel<<<NG, 256, 0, stream>>>(src, dst, counts, staging, E);
    bfinal_kernel<<<NB, 256, 0, stream>>>(btot, staging, csr, row_beg, row_end, dis, x, xh, N);

    // ---- fused layer1 + layer2-GEMM: zh = (relu(gather(xh)@W1+b1)@W2)*dis ----
    gfuse_kernel<<<N / 16, 1024, 0, stream>>>(xh, dis, W1t, b1, W2t, row_beg, row_end, csr, zh, N, 1.0f);

    // ---- final gather: out = gather(zh) + b2 ----
    gather2_kernel<<<N / 4, 256, 0, stream>>>(zh, dis, b2, row_beg, row_end, csr, out, N, 1.0f);
}

// Round 16
// 162.664 us; speedup vs baseline: 1.1358x; 1.1041x over previous
//
#include <hip/hip_runtime.h>
#include <hip/hip_fp16.h>

#define NN 100000
#define NB 391        // ceil(NN/256) buckets of 256 dst nodes
#define NG 512        // edge-pass blocks
#define REGION 6144   // padded per-bucket staging/csr region

using f16x8 = __attribute__((ext_vector_type(8))) _Float16;
using f32x4 = __attribute__((ext_vector_type(4))) float;

// ---------------- pass A: per-block bucket histogram (LDS), counts[NG][NB] ----------------
__global__ __launch_bounds__(256) void bhist_kernel(const int* __restrict__ dst,
                                                    int* __restrict__ counts, int E) {
    __shared__ int h[NB];
    for (int i = threadIdx.x; i < NB; i += 256) h[i] = 0;
    __syncthreads();
    const int g = blockIdx.x;
    const int chunk = (E + NG - 1) / NG;
    const int lo = g * chunk, hi = min(E, lo + chunk);
    for (int e = lo + threadIdx.x; e < hi; e += 256) atomicAdd(&h[dst[e] >> 8], 1);
    __syncthreads();
    for (int i = threadIdx.x; i < NB; i += 256) counts[g * NB + i] = h[i];
}

// ---------------- pass B: per-bucket prefix over NG entries (padded regions) + folded cvtW ----------------
__global__ __launch_bounds__(256) void bprefix_kernel(int* __restrict__ counts,
                                                      int* __restrict__ btot,
                                                      const float* __restrict__ W1,
                                                      const float* __restrict__ W2,
                                                      __half* __restrict__ W1t,
                                                      __half* __restrict__ W2t) {
    const int b = blockIdx.x, t = threadIdx.x;
    if (b == NB) {
        for (int i = t; i < 64 * 128; i += 256) {
            int k = i / 128, c = i % 128;
            W1t[c * 64 + k] = __float2half(W1[i]);
            int k2 = i / 64, c2 = i % 64;
            W2t[c2 * 128 + k2] = __float2half(W2[i]);
        }
        return;
    }
    __shared__ int sm[256];
    int loc[NG / 256];
    int s = 0;
    #pragma unroll
    for (int p = 0; p < NG / 256; ++p) {
        loc[p] = counts[((NG / 256) * t + p) * NB + b];
        s += loc[p];
    }
    sm[t] = s; __syncthreads();
    for (int off = 1; off < 256; off <<= 1) {
        int x = (t >= off) ? sm[t - off] : 0; __syncthreads();
        sm[t] += x; __syncthreads();
    }
    int run = b * REGION + sm[t] - s;
    #pragma unroll
    for (int p = 0; p < NG / 256; ++p) {
        int c = loc[p];
        counts[((NG / 256) * t + p) * NB + b] = run;
        run += c;
    }
    if (t == 255) btot[b] = sm[255];
}

// ---------------- pass C: scatter edges into bucket-region staging ----------------
__global__ __launch_bounds__(256) void bscatter_kernel(const int* __restrict__ src,
                                                       const int* __restrict__ dst,
                                                       const int* __restrict__ cstart,
                                                       int* __restrict__ staging, int E) {
    __shared__ int cur[NB];
    const int g = blockIdx.x;
    for (int i = threadIdx.x; i < NB; i += 256) cur[i] = cstart[g * NB + i];
    __syncthreads();
    const int chunk = (E + NG - 1) / NG;
    const int lo = g * chunk, hi = min(E, lo + chunk);
    for (int e = lo + threadIdx.x; e < hi; e += 256) {
        int d = dst[e];
        int pos = atomicAdd(&cur[d >> 8], 1);
        staging[pos] = src[e] | ((d & 255) << 17);
    }
}

// ---------------- pass D: per-bucket CSR finalize + row_beg/end + dis + x->fp16 ----------------
__global__ __launch_bounds__(256) void bfinal_kernel(const int* __restrict__ btot,
                                                     const int* __restrict__ staging,
                                                     int* __restrict__ csr,
                                                     int* __restrict__ row_beg,
                                                     int* __restrict__ row_end,
                                                     float* __restrict__ dis,
                                                     const float* __restrict__ x,
                                                     __half* __restrict__ xh,
                                                     int N) {
    __shared__ int h[256];
    __shared__ int sc[256];
    __shared__ int cur[256];
    __shared__ float sdis[256];
    const int b = blockIdx.x, t = threadIdx.x;
    const int base = b * REGION;
    const int endb = base + btot[b];
    h[t] = 0; __syncthreads();
    for (int i = base + t; i < endb; i += 256) atomicAdd(&h[staging[i] >> 17], 1);
    __syncthreads();
    int v = h[t];
    sc[t] = v; __syncthreads();
    for (int off = 1; off < 256; off <<= 1) {
        int xv = (t >= off) ? sc[t - off] : 0; __syncthreads();
        sc[t] += xv; __syncthreads();
    }
    int excl = sc[t] - v;
    cur[t] = base + excl;
    float dv = rsqrtf((float)v + 1.0f);
    sdis[t] = dv;
    int node = b * 256 + t;
    if (node < N) {
        row_beg[node] = base + excl;
        row_end[node] = base + excl + v;
        dis[node] = dv;
    }
    __syncthreads();
    for (int i = base + t; i < endb; i += 256) {
        int p = staging[i];
        int pos = atomicAdd(&cur[p >> 17], 1);
        csr[pos] = p & 0x1FFFF;
    }
    // fused: xh[node] = dis[node]*x[node] (fp16, row-major)
    const int node0 = b * 256;
    const int nmax = min(256, N - node0);
    for (int i = t; i < nmax * 16; i += 256) {
        int nl = i >> 4, c4 = i & 15;
        float4 vx = ((const float4*)x)[(size_t)(node0 + nl) * 16 + c4];
        float wq = sdis[nl];
        __half2* o = (__half2*)&xh[(size_t)(node0 + nl) * 64 + c4 * 4];
        o[0] = __floats2half2_rn(vx.x * wq, vx.y * wq);
        o[1] = __floats2half2_rn(vx.z * wq, vx.w * wq);
    }
}

// ---------------- fused layer1+layer2-GEMM: zh = (relu(gather(xh)@W1+b1) @ W2) * dis ----------------
// 512 threads, 16 nodes/block. Gather: 32 lanes/node (4 edge slots x 8 col-octets),
// 16 edges per iteration (4 loads in flight per lane).
__global__ __launch_bounds__(512) void gfuse_kernel(const __half* __restrict__ tab,
                                                    const float* __restrict__ dis,
                                                    const __half* __restrict__ W1t,
                                                    const float* __restrict__ b1,
                                                    const __half* __restrict__ W2t,
                                                    const int* __restrict__ row_beg,
                                                    const int* __restrict__ row_end,
                                                    const int* __restrict__ csr,
                                                    __half* __restrict__ zh, int N,
                                                    float one) {
    __shared__ _Float16 sA[16][72];    // 16x64 agg tile (dis-scaled), padded
    __shared__ _Float16 sH[16][132];   // 16x128 h1 tile, 264B stride (conflict-reduced)
    __shared__ float sP[4][16][16];    // gemm2 K-half partials
    const int tid = threadIdx.x;
    const int nodeL = tid >> 5;
    const int l32 = tid & 31;
    const int e = l32 >> 3;           // edge slot 0..3
    const int sub = l32 & 7;          // col octet
    const int node0 = blockIdx.x * 16;
    const int node = node0 + nodeL;
    const int beg = row_beg[node], end = row_end[node];

    float acc[8];
    {   // self loop counted once via slot 0 (dis[s] folded in tab)
        f16x8 sv = *reinterpret_cast<const f16x8*>(&tab[(size_t)node * 64 + sub * 8]);
        #pragma unroll
        for (int q = 0; q < 8; ++q) acc[q] = (e == 0) ? (float)sv[q] : 0.0f;
    }
    int j = beg;
    for (; j + 16 <= end; j += 16) {          // 4 loads in flight per lane
        int s0 = csr[j + e];
        int s1 = csr[j + 4 + e];
        int s2 = csr[j + 8 + e];
        int s3 = csr[j + 12 + e];
        f16x8 v0 = *reinterpret_cast<const f16x8*>(&tab[(size_t)s0 * 64 + sub * 8]);
        f16x8 v1 = *reinterpret_cast<const f16x8*>(&tab[(size_t)s1 * 64 + sub * 8]);
        f16x8 v2 = *reinterpret_cast<const f16x8*>(&tab[(size_t)s2 * 64 + sub * 8]);
        f16x8 v3 = *reinterpret_cast<const f16x8*>(&tab[(size_t)s3 * 64 + sub * 8]);
        #pragma unroll
        for (int q = 0; q < 8; ++q) acc[q] = fmaf((float)v0[q], one, acc[q]);
        #pragma unroll
        for (int q = 0; q < 8; ++q) acc[q] = fmaf((float)v1[q], one, acc[q]);
        #pragma unroll
        for (int q = 0; q < 8; ++q) acc[q] = fmaf((float)v2[q], one, acc[q]);
        #pragma unroll
        for (int q = 0; q < 8; ++q) acc[q] = fmaf((float)v3[q], one, acc[q]);
    }
    if (j + 8 <= end) {                        // 2 loads in flight
        int s0 = csr[j + e];
        int s1 = csr[j + 4 + e];
        f16x8 v0 = *reinterpret_cast<const f16x8*>(&tab[(size_t)s0 * 64 + sub * 8]);
        f16x8 v1 = *reinterpret_cast<const f16x8*>(&tab[(size_t)s1 * 64 + sub * 8]);
        #pragma unroll
        for (int q = 0; q < 8; ++q) acc[q] = fmaf((float)v0[q], one, acc[q]);
        #pragma unroll
        for (int q = 0; q < 8; ++q) acc[q] = fmaf((float)v1[q], one, acc[q]);
        j += 8;
    }
    if (j + 4 <= end) {
        int s0 = csr[j + e];
        f16x8 v0 = *reinterpret_cast<const f16x8*>(&tab[(size_t)s0 * 64 + sub * 8]);
        #pragma unroll
        for (int q = 0; q < 8; ++q) acc[q] = fmaf((float)v0[q], one, acc[q]);
        j += 4;
    }
    if (j + e < end) {                         // masked tail
        int s0 = csr[j + e];
        f16x8 v0 = *reinterpret_cast<const f16x8*>(&tab[(size_t)s0 * 64 + sub * 8]);
        #pragma unroll
        for (int q = 0; q < 8; ++q) acc[q] = fmaf((float)v0[q], one, acc[q]);
    }
    #pragma unroll
    for (int q = 0; q < 8; ++q) {
        acc[q] += __shfl_xor(acc[q], 8);
        acc[q] += __shfl_xor(acc[q], 16);
    }
    if (e == 0) {
        const float dd = dis[node];
        f16x8 o;
        #pragma unroll
        for (int q = 0; q < 8; ++q) o[q] = (_Float16)(acc[q] * dd);
        *reinterpret_cast<f16x8*>(&sA[nodeL][sub * 8]) = o;
    }
    __syncthreads();

    const int w = tid >> 6, lane = tid & 63;
    const int lrow = lane & 15, kgrp = lane >> 4;
    // ---- gemm1: h1 = relu(sA @ W1 + b1), 8 waves x 16 cols, K=64 ----
    {
        const int col = w * 16 + lrow;
        f32x4 a1 = (f32x4){0.f, 0.f, 0.f, 0.f};
        #pragma unroll
        for (int ks = 0; ks < 2; ++ks) {
            const int kbase = ks * 32 + kgrp * 8;
            f16x8 a  = *reinterpret_cast<const f16x8*>(&sA[lrow][kbase]);
            f16x8 bf = *reinterpret_cast<const f16x8*>(&W1t[(size_t)col * 64 + kbase]);
            a1 = __builtin_amdgcn_mfma_f32_16x16x32_f16(a, bf, a1, 0, 0, 0);
        }
        const float bb = b1[col];
        #pragma unroll
        for (int r = 0; r < 4; ++r) {
            const int row = kgrp * 4 + r;
            sH[row][col] = (_Float16)fmaxf(a1[r] + bb, 0.0f);
        }
    }
    __syncthreads();
    // ---- gemm2 split-K: zh = (sH @ W2) * dis, 4 col tiles x 2 K-halves ----
    {
        const int t2 = w & 3, kh = w >> 2;
        const int col = t2 * 16 + lrow;
        f32x4 a2 = (f32x4){0.f, 0.f, 0.f, 0.f};
        #pragma unroll
        for (int ks = 0; ks < 2; ++ks) {
            const int kbase = kh * 64 + ks * 32 + kgrp * 8;
            f16x8 a  = *reinterpret_cast<const f16x8*>(&sH[lrow][kbase]);
            f16x8 bf = *reinterpret_cast<const f16x8*>(&W2t[(size_t)col * 128 + kbase]);
            a2 = __builtin_amdgcn_mfma_f32_16x16x32_f16(a, bf, a2, 0, 0, 0);
        }
        if (kh == 1) {
            #pragma unroll
            for (int r = 0; r < 4; ++r) sP[t2][kgrp * 4 + r][lrow] = a2[r];
        }
        __syncthreads();
        if (kh == 0) {
            #pragma unroll
            for (int r = 0; r < 4; ++r) {
                const int row = kgrp * 4 + r;
                float v = (a2[r] + sP[t2][row][lrow]) * dis[node0 + row];
                zh[(size_t)(node0 + row) * 64 + col] = __float2half(v);
            }
        }
    }
}

// ---------------- gather2: 1 wave/node, 16 edges/iter, out fp32 + bias ----------------
__global__ __launch_bounds__(256) void gather2_kernel(const __half* __restrict__ tab,
                                                      const float* __restrict__ dis,
                                                      const float* __restrict__ b,
                                                      const int* __restrict__ row_beg,
                                                      const int* __restrict__ row_end,
                                                      const int* __restrict__ csr,
                                                      float* __restrict__ out, int N,
                                                      float one) {
    const int node = blockIdx.x * 4 + (threadIdx.x >> 6);
    const int lane = threadIdx.x & 63;
    const int g   = lane >> 3;
    const int sub = lane & 7;
    if (node >= N) return;
    const int beg = row_beg[node], end = row_end[node];

    float acc[8];
    {
        f16x8 sv = *reinterpret_cast<const f16x8*>(&tab[(size_t)node * 64 + sub * 8]);
        #pragma unroll
        for (int q = 0; q < 8; ++q) acc[q] = (g == 0) ? (float)sv[q] : 0.0f;
    }
    int j = beg;
    for (; j + 16 <= end; j += 16) {
        int sA = csr[j + g];
        int sB = csr[j + 8 + g];
        f16x8 vA = *reinterpret_cast<const f16x8*>(&tab[(size_t)sA * 64 + sub * 8]);
        f16x8 vB = *reinterpret_cast<const f16x8*>(&tab[(size_t)sB * 64 + sub * 8]);
        #pragma unroll
        for (int q = 0; q < 8; ++q) acc[q] = fmaf((float)vA[q], one, acc[q]);
        #pragma unroll
        for (int q = 0; q < 8; ++q) acc[q] = fmaf((float)vB[q], one, acc[q]);
    }
    if (j + 8 <= end) {
        int s = csr[j + g];
        f16x8 v = *reinterpret_cast<const f16x8*>(&tab[(size_t)s * 64 + sub * 8]);
        #pragma unroll
        for (int q = 0; q < 8; ++q) acc[q] = fmaf((float)v[q], one, acc[q]);
        j += 8;
    }
    if (j + g < end) {
        int s = csr[j + g];
        f16x8 v = *reinterpret_cast<const f16x8*>(&tab[(size_t)s * 64 + sub * 8]);
        #pragma unroll
        for (int q = 0; q < 8; ++q) acc[q] = fmaf((float)v[q], one, acc[q]);
    }
    #pragma unroll
    for (int q = 0; q < 8; ++q) {
        acc[q] += __shfl_xor(acc[q], 8);
        acc[q] += __shfl_xor(acc[q], 16);
        acc[q] += __shfl_xor(acc[q], 32);
    }
    if (g == 0) {
        const float dd = dis[node];
        float vv[8];
        #pragma unroll
        for (int q = 0; q < 8; ++q) vv[q] = acc[q] * dd + b[sub * 8 + q];
        float* op = &out[(size_t)node * 64 + sub * 8];
        *reinterpret_cast<float4*>(op)     = make_float4(vv[0], vv[1], vv[2], vv[3]);
        *reinterpret_cast<float4*>(op + 4) = make_float4(vv[4], vv[5], vv[6], vv[7]);
    }
}

extern "C" void kernel_launch(void* const* d_in, const int* in_sizes, int n_in,
                              void* d_out, int out_size, void* d_ws, size_t ws_size,
                              hipStream_t stream) {
    const float* x  = (const float*)d_in[0];
    const int*   ei = (const int*)d_in[1];
    const float* W1 = (const float*)d_in[2];
    const float* b1 = (const float*)d_in[3];
    const float* W2 = (const float*)d_in[4];
    const float* b2 = (const float*)d_in[5];
    float* out = (float*)d_out;

    const int N = NN;
    const int E = in_sizes[1] / 2;
    const int* src = ei;
    const int* dst = ei + E;

    // workspace layout (4-byte words)
    int* counts   = (int*)d_ws;                       // NG*NB
    int* btot     = counts + NG * NB;                 // NB (+pad)
    int* row_beg  = btot + 512;                       // N
    int* row_end  = row_beg + N;                      // N
    float* dis    = (float*)(row_end + N);            // N
    int* staging  = (int*)(dis + N);                  // NB*REGION
    int* csr      = staging + (size_t)NB * REGION;    // NB*REGION
    float* base   = (float*)(csr + (size_t)NB * REGION);
    __half* xh    = (__half*)base;                        // N*64 halves
    __half* zh    = (__half*)(base + (size_t)N * 32);     // N*64 halves
    __half* W1t   = (__half*)(base + (size_t)N * 64);     // 8192 halves
    __half* W2t   = W1t + 128 * 64;                       // 8192 halves

    // ---- CSR build (R12 structure) ----
    bhist_kernel<<<NG, 256, 0, stream>>>(dst, counts, E);
    bprefix_kernel<<<NB + 1, 256, 0, stream>>>(counts, btot, W1, W2, W1t, W2t);
    bscatter_kernel<<<NG, 256, 0, stream>>>(src, dst, counts, staging, E);
    bfinal_kernel<<<NB, 256, 0, stream>>>(btot, staging, csr, row_beg, row_end, dis, x, xh, N);

    // ---- fused layer1 + layer2-GEMM: zh = (relu(gather(xh)@W1+b1)@W2)*dis ----
    gfuse_kernel<<<N / 16, 512, 0, stream>>>(xh, dis, W1t, b1, W2t, row_beg, row_end, csr, zh, N, 1.0f);

    // ---- final gather: out = gather(zh) + b2 ----
    gather2_kernel<<<N / 4, 256, 0, stream>>>(zh, dis, b2, row_beg, row_end, csr, out, N, 1.0f);
}